// Round 1
// baseline (239.507 us; speedup 1.0000x reference)
//
#include <hip/hip_runtime.h>
#include <hip/hip_bf16.h>

// Sizes
#define Bb 16
#define Gg 2048
#define Dd 2048
#define Ee 32
#define XS 4097   // G + D + 1
#define EPSf 1e-5f

__device__ inline float fast_exp2(float x) {
#if __has_builtin(__builtin_amdgcn_exp2f)
  return __builtin_amdgcn_exp2f(x);
#else
  return exp2f(x);
#endif
}

__device__ inline float wred(float v) {
  // butterfly sum across 64-lane wave; all lanes get total
  #pragma unroll
  for (int o = 32; o > 0; o >>= 1) v += __shfl_xor(v, o, 64);
  return v;
}

// ---------------- K0: transpose W_rbf (32,2048) -> WT (2048,32) ----------
__global__ __launch_bounds__(256) void k_wt(const float* __restrict__ Wr,
                                            float* __restrict__ WT) {
  int f = blockIdx.x * 256 + threadIdx.x;   // 65536
  int j = f >> 5, e = f & 31;
  WT[f] = Wr[e * Gg + j];
}

// ---------------- K1: RBF partial sums ----------------------------------
// partA[jc][b][e][i], jc in 0..3 (j-chunks of 512)
__global__ __launch_bounds__(256) void k_rbf(const float* __restrict__ x,
                                             const float* __restrict__ WT,
                                             float* __restrict__ part) {
  const int i  = blockIdx.x * 256 + threadIdx.x;   // 0..2047
  const int b  = blockIdx.y;
  const int jc = blockIdx.z;
  const float gi = x[b * XS + i];
  float acc[32];
  #pragma unroll
  for (int e = 0; e < 32; ++e) acc[e] = 0.f;
  const float* xb = x + b * XS;
  const int j0 = jc * 512;
  for (int j = j0; j < j0 + 512; ++j) {
    float gj = xb[j];                       // wave-uniform -> s_load
    float d  = gi - gj;
    float t  = d * d * (-0.72134752044448170368f);  // -gamma*log2(e)
    float k  = fast_exp2(t);
    const float* w = WT + j * 32;           // wave-uniform -> s_load
    #pragma unroll
    for (int e = 0; e < 32; ++e) acc[e] = fmaf(k, w[e], acc[e]);
  }
  float* p = part + (((size_t)jc * Bb + b) * 32) * Gg + i;
  #pragma unroll
  for (int e = 0; e < 32; ++e) p[(size_t)e * Gg] = acc[e];
}

// ---------------- K2: reduce partials + bias + emb gather -> gf (b,e,i) --
__global__ __launch_bounds__(256) void k_gf(const float* __restrict__ part,
                                            const float* __restrict__ x,
                                            const int* __restrict__ table,
                                            const float* __restrict__ emb,
                                            const float* __restrict__ brbf,
                                            float* __restrict__ gf) {
  int flat = blockIdx.x * 256 + threadIdx.x;   // 1,048,576
  int i = flat & 2047;
  int e = (flat >> 11) & 31;
  int b = flat >> 16;
  float s = part[flat] + part[1048576 + flat] + part[2 * 1048576 + flat] +
            part[3 * 1048576 + flat];
  int idx = (int)x[b * XS + Gg + Dd];
  int t   = table[idx * Gg + i];
  float lv = emb[t * 32 + e];
  gf[flat] = s + brbf[e] + lv;
}

// ---------------- K3: matmul gf(512x2048) x Wdg(1024x2048)^T -------------
// partB[kc][m][n], kc in 0..1 (K halves of 1024)
__global__ __launch_bounds__(256) void k_mm(const float* __restrict__ A,
                                            const float* __restrict__ Bm,
                                            float* __restrict__ part) {
  __shared__ float As[32][64];
  __shared__ float Bs[32][64];
  const int tid = threadIdx.x;
  const int n0 = blockIdx.x * 64;
  const int m0 = blockIdx.y * 64;
  const int kc = blockIdx.z;
  const int lr = tid >> 2;          // 0..63
  const int lk = (tid & 3) * 8;     // 0,8,16,24
  const int ty = tid >> 4;          // 0..15
  const int tx = tid & 15;
  float acc[4][4];
  #pragma unroll
  for (int r = 0; r < 4; ++r)
    #pragma unroll
    for (int c = 0; c < 4; ++c) acc[r][c] = 0.f;
  const float* Ar = A  + (size_t)(m0 + lr) * 2048 + lk;
  const float* Br = Bm + (size_t)(n0 + lr) * 2048 + lk;
  const int kend = kc * 1024 + 1024;
  for (int kb = kc * 1024; kb < kend; kb += 32) {
    float4 a0 = *(const float4*)(Ar + kb);
    float4 a1 = *(const float4*)(Ar + kb + 4);
    float4 b0 = *(const float4*)(Br + kb);
    float4 b1 = *(const float4*)(Br + kb + 4);
    __syncthreads();
    As[lk + 0][lr] = a0.x; As[lk + 1][lr] = a0.y;
    As[lk + 2][lr] = a0.z; As[lk + 3][lr] = a0.w;
    As[lk + 4][lr] = a1.x; As[lk + 5][lr] = a1.y;
    As[lk + 6][lr] = a1.z; As[lk + 7][lr] = a1.w;
    Bs[lk + 0][lr] = b0.x; Bs[lk + 1][lr] = b0.y;
    Bs[lk + 2][lr] = b0.z; Bs[lk + 3][lr] = b0.w;
    Bs[lk + 4][lr] = b1.x; Bs[lk + 5][lr] = b1.y;
    Bs[lk + 6][lr] = b1.z; Bs[lk + 7][lr] = b1.w;
    __syncthreads();
    #pragma unroll
    for (int kk = 0; kk < 32; ++kk) {
      float4 av = *(const float4*)&As[kk][ty * 4];
      float4 bv = *(const float4*)&Bs[kk][tx * 4];
      acc[0][0] = fmaf(av.x, bv.x, acc[0][0]);
      acc[0][1] = fmaf(av.x, bv.y, acc[0][1]);
      acc[0][2] = fmaf(av.x, bv.z, acc[0][2]);
      acc[0][3] = fmaf(av.x, bv.w, acc[0][3]);
      acc[1][0] = fmaf(av.y, bv.x, acc[1][0]);
      acc[1][1] = fmaf(av.y, bv.y, acc[1][1]);
      acc[1][2] = fmaf(av.y, bv.z, acc[1][2]);
      acc[1][3] = fmaf(av.y, bv.w, acc[1][3]);
      acc[2][0] = fmaf(av.z, bv.x, acc[2][0]);
      acc[2][1] = fmaf(av.z, bv.y, acc[2][1]);
      acc[2][2] = fmaf(av.z, bv.z, acc[2][2]);
      acc[2][3] = fmaf(av.z, bv.w, acc[2][3]);
      acc[3][0] = fmaf(av.w, bv.x, acc[3][0]);
      acc[3][1] = fmaf(av.w, bv.y, acc[3][1]);
      acc[3][2] = fmaf(av.w, bv.z, acc[3][2]);
      acc[3][3] = fmaf(av.w, bv.w, acc[3][3]);
    }
  }
  float* o = part + (size_t)kc * 524288 + (size_t)(m0 + ty * 4) * 1024 + n0 + tx * 4;
  #pragma unroll
  for (int r = 0; r < 4; ++r) {
    float4 st = make_float4(acc[r][0], acc[r][1], acc[r][2], acc[r][3]);
    *(float4*)(o + (size_t)r * 1024) = st;
  }
}

// ---------------- K4: reduce K-halves + bias -> gene_out (l,b,e,gs) ------
__global__ __launch_bounds__(256) void k_gout(const float* __restrict__ part,
                                              const float* __restrict__ bdg,
                                              float* __restrict__ gout) {
  int flat = blockIdx.x * 256 + threadIdx.x;   // 524288
  int m = flat >> 10, n = flat & 1023;
  float v = part[flat] + part[524288 + flat] + bdg[n];
  int l = n >> 6, kgs = n & 63, b = m >> 5, e = m & 31;
  gout[(((size_t)l * Bb + b) * 32 + e) * 64 + kgs] = v;
}

// ---------------- batchnorm over 512 threads, 6 channels -----------------
__device__ inline void bn512(float* v, int wv, int lane,
                             float (*r1)[6], float (*r2)[6]) {
  float s[6], q[6];
  #pragma unroll
  for (int c = 0; c < 6; ++c) {
    float a = v[c];
    s[c] = wred(a);
    q[c] = wred(a * a);
  }
  __syncthreads();   // WAR protection for LDS reuse
  if (lane == 0) {
    #pragma unroll
    for (int c = 0; c < 6; ++c) { r1[wv][c] = s[c]; r2[wv][c] = q[c]; }
  }
  __syncthreads();
  #pragma unroll
  for (int c = 0; c < 6; ++c) {
    float S = 0.f, Q = 0.f;
    #pragma unroll
    for (int w = 0; w < 8; ++w) { S += r1[w][c]; Q += r2[w][c]; }
    float m  = S * (1.0f / 512.0f);
    float va = Q * (1.0f / 512.0f) - m * m;
    v[c] = (v[c] - m) * rsqrtf(va + EPSf);
  }
}

// ---------------- K5/K6: _term 3d part (leaf: IN=64 MODE=0, mid: IN=24 MODE=1)
template <int IN, int MODE>
__global__ __launch_bounds__(512) void k_term(const float* __restrict__ gin,
                                              const float* __restrict__ W1,
                                              const float* __restrict__ b1,
                                              const float* __restrict__ Wc,
                                              const float* __restrict__ bc,
                                              float* __restrict__ outp) {
  const int l = blockIdx.x, tid = threadIdx.x;
  const int wv = tid >> 6, lane = tid & 63;
  __shared__ float r1[8][6], r2[8][6];
  const float* ci = gin + ((size_t)l * 512 + tid) * IN;
  float cv[IN];
  #pragma unroll
  for (int q = 0; q < IN / 4; ++q)
    *(float4*)&cv[q * 4] = ((const float4*)ci)[q];
  const float* w1 = W1 + l * 6 * IN;
  float h[6];
  #pragma unroll
  for (int hh = 0; hh < 6; ++hh) {
    float s = b1[l * 6 + hh];
    #pragma unroll
    for (int i = 0; i < IN; ++i) s = fmaf(cv[i], w1[hh * IN + i], s);
    h[hh] = s;
  }
  bn512(h, wv, lane, r1, r2);
  float c[6];
  #pragma unroll
  for (int k = 0; k < 6; ++k) {
    float s = bc[l * 6 + k];
    #pragma unroll
    for (int hh = 0; hh < 6; ++hh) s = fmaf(h[hh], Wc[l * 36 + k * 6 + hh], s);
    c[k] = s;
  }
  bn512(c, wv, lane, r1, r2);
  if (MODE == 0) {
    float* o = outp + (((size_t)(l >> 2) * 512 + tid) * 24 + (l & 3) * 6);
    #pragma unroll
    for (int k = 0; k < 6; ++k) o[k] = c[k];
  } else {
    float* o = outp + ((size_t)tid * 24 + l * 6);
    #pragma unroll
    for (int k = 0; k < 6; ++k) o[k] = c[k];
  }
}

// ---------------- K7: root term (full, with out2d) -----------------------
__global__ __launch_bounds__(512) void k_root(const float* __restrict__ rootin,
                                              const float* __restrict__ Wr1,
                                              const float* __restrict__ br1,
                                              const float* __restrict__ Wrc,
                                              const float* __restrict__ brc,
                                              const float* __restrict__ Wrd,
                                              const float* __restrict__ brd,
                                              float* __restrict__ r2d) {
  const int tid = threadIdx.x;
  const int wv = tid >> 6, lane = tid & 63;
  __shared__ float r1[8][6], r2[8][6];
  const float* ci = rootin + (size_t)tid * 24;
  float cv[24];
  #pragma unroll
  for (int q = 0; q < 6; ++q) *(float4*)&cv[q * 4] = ((const float4*)ci)[q];
  float h[6];
  #pragma unroll
  for (int hh = 0; hh < 6; ++hh) {
    float s = br1[hh];
    #pragma unroll
    for (int i = 0; i < 24; ++i) s = fmaf(cv[i], Wr1[hh * 24 + i], s);
    h[hh] = s;
  }
  bn512(h, wv, lane, r1, r2);
  float c[6];
  #pragma unroll
  for (int k = 0; k < 6; ++k) {
    float s = brc[k];
    #pragma unroll
    for (int hh = 0; hh < 6; ++hh) s = fmaf(h[hh], Wrc[k * 6 + hh], s);
    c[k] = s;
  }
  bn512(c, wv, lane, r1, r2);
  float mv = (c[0] + c[1] + c[2] + c[3] + c[4] + c[5]) * (1.0f / 6.0f);
  __shared__ float shm[512];
  shm[tid] = mv;
  __syncthreads();
  __shared__ float st[96];
  if (tid < 96) {
    int b = tid / 6, hh = tid % 6;
    float s = brd[hh];
    #pragma unroll
    for (int e = 0; e < 32; ++e) s = fmaf(shm[b * 32 + e], Wrd[hh * 32 + e], s);
    st[tid] = tanhf(s);
  }
  __syncthreads();
  if (tid < 6) {
    float S = 0.f, Q = 0.f;
    for (int b = 0; b < 16; ++b) { float v = st[b * 6 + tid]; S += v; Q += v * v; }
    float m = S * (1.0f / 16.0f), va = Q * (1.0f / 16.0f) - m * m;
    float iv = rsqrtf(va + EPSf);
    for (int b = 0; b < 16; ++b) r2d[b * 6 + tid] = (st[b * 6 + tid] - m) * iv;
  }
}

// ---------------- K8: drug layer 1 (per-column block) --------------------
__global__ __launch_bounds__(256) void k_drug1(const float* __restrict__ x,
                                               const float* __restrict__ Wd1,
                                               const float* __restrict__ bd1,
                                               float* __restrict__ d1) {
  const int c = blockIdx.x;        // 0..99
  const int tid = threadIdx.x;
  const int b = tid >> 4, li = tid & 15;
  const float* xb = x + b * XS + Gg;
  const float* w = Wd1 + (size_t)c * 2048;
  float s = 0.f;
  for (int k = li; k < 2048; k += 16) s = fmaf(xb[k], w[k], s);
  __shared__ float red[256];
  red[tid] = s;
  __syncthreads();
  __shared__ float y[16];
  if (li == 0) {
    float t = 0.f;
    #pragma unroll
    for (int q = 0; q < 16; ++q) t += red[b * 16 + q];
    y[b] = tanhf(t + bd1[c]);
  }
  __syncthreads();
  if (tid < 16) {
    float S = 0.f, Q = 0.f;
    #pragma unroll
    for (int bb = 0; bb < 16; ++bb) { float v = y[bb]; S += v; Q += v * v; }
    float m = S * (1.0f / 16.0f), va = Q * (1.0f / 16.0f) - m * m;
    d1[tid * 100 + c] = (y[tid] - m) * rsqrtf(va + EPSf);
  }
}

// ---------------- K9: drug layers 2-3 + final head -----------------------
__global__ __launch_bounds__(512) void k_final(const float* __restrict__ d1,
                                               const float* __restrict__ r2d,
                                               const float* __restrict__ Wd2,
                                               const float* __restrict__ bd2,
                                               const float* __restrict__ Wd3,
                                               const float* __restrict__ bd3,
                                               const float* __restrict__ Wf,
                                               const float* __restrict__ bf,
                                               const float* __restrict__ Wfa,
                                               const float* __restrict__ bfa,
                                               const float* __restrict__ Wfo,
                                               const float* __restrict__ bfo,
                                               float* __restrict__ out) {
  const int tid = threadIdx.x;
  __shared__ float s2[800], mu2[50], iv2[50];
  for (int u = tid; u < 800; u += 512) {
    int b = u / 50, c = u % 50;
    float s = bd2[c];
    for (int k = 0; k < 100; ++k) s = fmaf(d1[b * 100 + k], Wd2[c * 100 + k], s);
    s2[u] = tanhf(s);
  }
  __syncthreads();
  if (tid < 50) {
    float S = 0.f, Q = 0.f;
    #pragma unroll
    for (int b = 0; b < 16; ++b) { float v = s2[b * 50 + tid]; S += v; Q += v * v; }
    float m = S * (1.0f / 16.0f), va = Q * (1.0f / 16.0f) - m * m;
    mu2[tid] = m; iv2[tid] = rsqrtf(va + EPSf);
  }
  __syncthreads();
  __shared__ float s3[96], mu3[6], iv3[6];
  if (tid < 96) {
    int b = tid / 6, c = tid % 6;
    float s = bd3[c];
    for (int k = 0; k < 50; ++k)
      s = fmaf((s2[b * 50 + k] - mu2[k]) * iv2[k], Wd3[c * 50 + k], s);
    s3[tid] = tanhf(s);
  }
  __syncthreads();
  if (tid < 6) {
    float S = 0.f, Q = 0.f;
    #pragma unroll
    for (int b = 0; b < 16; ++b) { float v = s3[b * 6 + tid]; S += v; Q += v * v; }
    float m = S * (1.0f / 16.0f), va = Q * (1.0f / 16.0f) - m * m;
    mu3[tid] = m; iv3[tid] = rsqrtf(va + EPSf);
  }
  __syncthreads();
  __shared__ float sf[96], muf[6], ivf[6];
  if (tid < 96) {
    int b = tid / 6, c = tid % 6;
    float s = bf[c];
    #pragma unroll
    for (int q = 0; q < 6; ++q) s = fmaf(r2d[b * 6 + q], Wf[c * 12 + q], s);
    #pragma unroll
    for (int q = 0; q < 6; ++q)
      s = fmaf((s3[b * 6 + q] - mu3[q]) * iv3[q], Wf[c * 12 + 6 + q], s);
    sf[tid] = tanhf(s);
  }
  __syncthreads();
  if (tid < 6) {
    float S = 0.f, Q = 0.f;
    #pragma unroll
    for (int b = 0; b < 16; ++b) { float v = sf[b * 6 + tid]; S += v; Q += v * v; }
    float m = S * (1.0f / 16.0f), va = Q * (1.0f / 16.0f) - m * m;
    muf[tid] = m; ivf[tid] = rsqrtf(va + EPSf);
  }
  __syncthreads();
  if (tid < 16) {
    float s = bfa[0];
    #pragma unroll
    for (int q = 0; q < 6; ++q)
      s = fmaf((sf[tid * 6 + q] - muf[q]) * ivf[q], Wfa[q], s);
    float a = tanhf(s);
    out[tid] = a * Wfo[0] + bfo[0];
  }
}

extern "C" void kernel_launch(void* const* d_in, const int* in_sizes, int n_in,
                              void* d_out, int out_size, void* d_ws, size_t ws_size,
                              hipStream_t stream) {
  const float* x     = (const float*)d_in[0];
  const int*   table = (const int*)d_in[1];
  const float* Wrbf  = (const float*)d_in[2];
  const float* brbf  = (const float*)d_in[3];
  const float* emb   = (const float*)d_in[4];
  const float* Wdg   = (const float*)d_in[5];
  const float* bdg   = (const float*)d_in[6];
  const float* Wl1   = (const float*)d_in[7];
  const float* bl1   = (const float*)d_in[8];
  const float* Wlc   = (const float*)d_in[9];
  const float* blc   = (const float*)d_in[10];
  const float* Wm1   = (const float*)d_in[13];
  const float* bm1   = (const float*)d_in[14];
  const float* Wmc   = (const float*)d_in[15];
  const float* bmc   = (const float*)d_in[16];
  const float* Wr1   = (const float*)d_in[19];
  const float* br1   = (const float*)d_in[20];
  const float* Wrc   = (const float*)d_in[21];
  const float* brc   = (const float*)d_in[22];
  const float* Wrd   = (const float*)d_in[23];
  const float* brd   = (const float*)d_in[24];
  const float* Wd1   = (const float*)d_in[25];
  const float* bd1   = (const float*)d_in[26];
  const float* Wd2   = (const float*)d_in[27];
  const float* bd2   = (const float*)d_in[28];
  const float* Wd3   = (const float*)d_in[29];
  const float* bd3   = (const float*)d_in[30];
  const float* Wf    = (const float*)d_in[31];
  const float* bf    = (const float*)d_in[32];
  const float* Wfa   = (const float*)d_in[33];
  const float* bfa   = (const float*)d_in[34];
  const float* Wfo   = (const float*)d_in[35];
  const float* bfo   = (const float*)d_in[36];
  float* out = (float*)d_out;

  float* w      = (float*)d_ws;
  float* WT     = w;                       // 65536
  float* partA  = WT + 65536;              // 4 * 1048576
  float* gf     = partA + 4 * 1048576;     // 1048576
  float* partB  = gf + 1048576;            // 2 * 524288
  float* gout   = partB + 2 * 524288;      // 524288
  float* midin  = gout + 524288;           // 49152
  float* rootin = midin + 49152;           // 12288
  float* r2d    = rootin + 12288;          // 96
  float* d1     = r2d + 96;                // 1600

  hipLaunchKernelGGL(k_wt,   dim3(256),       dim3(256), 0, stream, Wrbf, WT);
  hipLaunchKernelGGL(k_rbf,  dim3(8, 16, 4),  dim3(256), 0, stream, x, WT, partA);
  hipLaunchKernelGGL(k_gf,   dim3(4096),      dim3(256), 0, stream, partA, x, table, emb, brbf, gf);
  hipLaunchKernelGGL(k_mm,   dim3(16, 8, 2),  dim3(256), 0, stream, gf, Wdg, partB);
  hipLaunchKernelGGL(k_gout, dim3(2048),      dim3(256), 0, stream, partB, bdg, gout);
  hipLaunchKernelGGL((k_term<64, 0>), dim3(16), dim3(512), 0, stream, gout, Wl1, bl1, Wlc, blc, midin);
  hipLaunchKernelGGL((k_term<24, 1>), dim3(4),  dim3(512), 0, stream, midin, Wm1, bm1, Wmc, bmc, rootin);
  hipLaunchKernelGGL(k_root, dim3(1), dim3(512), 0, stream, rootin, Wr1, br1, Wrc, brc, Wrd, brd, r2d);
  hipLaunchKernelGGL(k_drug1, dim3(100), dim3(256), 0, stream, x, Wd1, bd1, d1);
  hipLaunchKernelGGL(k_final, dim3(1), dim3(512), 0, stream, d1, r2d, Wd2, bd2, Wd3, bd3,
                     Wf, bf, Wfa, bfa, Wfo, bfo, out);
}

// Round 2
// 148.135 us; speedup vs baseline: 1.6168x; 1.6168x over previous
//
#include <hip/hip_runtime.h>
#include <hip/hip_bf16.h>

// Sizes
#define Bb 16
#define Gg 2048
#define Dd 2048
#define XS 4097   // G + D + 1
#define EPSf 1e-5f
#define CEXP (-0.72134752044448170368f)   // -gamma * log2(e), gamma = 0.5

typedef unsigned int u32;
typedef __attribute__((ext_vector_type(8))) short bf16x8;
typedef __attribute__((ext_vector_type(4))) float f32x4;

union U16 { uint4 u; bf16x8 v; };

__device__ inline float fast_exp2(float x) {
#if __has_builtin(__builtin_amdgcn_exp2f)
  return __builtin_amdgcn_exp2f(x);
#else
  return exp2f(x);
#endif
}

// pack two f32 into one u32 of 2 bf16 (truncation): low half from a, high from b
__device__ inline u32 pk2(float a, float b) {
  return __builtin_amdgcn_perm(__float_as_uint(b), __float_as_uint(a), 0x07060302u);
}
__device__ inline float bftrunc(float a) {
  return __uint_as_float(__float_as_uint(a) & 0xFFFF0000u);
}

// split 8 floats into hi/lo bf16x8 fragments
__device__ inline void split8(const float* f, U16& hi, U16& lo) {
  u32 h[4], l[4];
  #pragma unroll
  for (int p = 0; p < 4; ++p) {
    float a = f[2 * p], b = f[2 * p + 1];
    h[p] = pk2(a, b);
    l[p] = pk2(a - bftrunc(a), b - bftrunc(b));
  }
  hi.u = make_uint4(h[0], h[1], h[2], h[3]);
  lo.u = make_uint4(l[0], l[1], l[2], l[3]);
}

__device__ inline float wred(float v) {
  #pragma unroll
  for (int o = 32; o > 0; o >>= 1) v += __shfl_xor(v, o, 64);
  return v;
}

// ---------------- K0: split weights into MFMA-frag-linear bf16 hi/lo ------
// Wrbf_pk[h(2)][ks(64)][l(64)] : e = h*16+(l&15), j = ks*32+(l>>4)*8+q
// Wdg_pk [nf(64)][ks(64)][l(64)]: n = nf*16+(l&15), k = ks*32+(l>>4)*8+q
__global__ __launch_bounds__(256) void k_split(const float* __restrict__ Wrbf,
                                               const float* __restrict__ Wdg,
                                               u32* __restrict__ Rhi, u32* __restrict__ Rlo,
                                               u32* __restrict__ Dhi, u32* __restrict__ Dlo) {
  int c = blockIdx.x * 256 + threadIdx.x;   // 270336 total
  const float* src;
  u32 *dhi, *dlo;
  if (c < 8192) {
    int h = c >> 12, ks = (c >> 6) & 63, l = c & 63;
    src = Wrbf + (h * 16 + (l & 15)) * Gg + ks * 32 + (l >> 4) * 8;
    dhi = Rhi + (size_t)c * 4; dlo = Rlo + (size_t)c * 4;
  } else {
    int cc = c - 8192;
    int nf = cc >> 12, ks = (cc >> 6) & 63, l = cc & 63;
    src = Wdg + (size_t)(nf * 16 + (l & 15)) * Gg + ks * 32 + (l >> 4) * 8;
    dhi = Dhi + (size_t)cc * 4; dlo = Dlo + (size_t)cc * 4;
  }
  float4 f0 = *(const float4*)src;
  float4 f1 = *(const float4*)(src + 4);
  float f[8] = {f0.x, f0.y, f0.z, f0.w, f1.x, f1.y, f1.z, f1.w};
  U16 hi, lo;
  split8(f, hi, lo);
  *(uint4*)dhi = hi.u;
  *(uint4*)dlo = lo.u;
}

// ---------------- K1: fused RBF einsum via MFMA; emits gf frag-linear -----
// grid (16 i-groups, 16 b), 512 threads = 8 waves; wave handles 16 i rows.
__global__ __launch_bounds__(512) void k_rbf(const float* __restrict__ x,
                                             const u32* __restrict__ Whi,
                                             const u32* __restrict__ Wlo,
                                             const int* __restrict__ table,
                                             const float* __restrict__ emb,
                                             const float* __restrict__ brbf,
                                             u32* __restrict__ Ahi,
                                             u32* __restrict__ Alo) {
  __shared__ float g_s[2048];
  __shared__ u32 w_s[8192];   // 32 segs x 256 u32 (1KB each)
  const int tid = threadIdx.x;
  const int lane = tid & 63, wid = tid >> 6;
  const int b = blockIdx.y;
  const int i0w = blockIdx.x * 128 + wid * 16;
  // stage g row
  #pragma unroll
  for (int q = 0; q < 4; ++q) g_s[tid * 4 + q] = x[(size_t)b * XS + tid * 4 + q];
  const float gi = x[(size_t)b * XS + i0w + (lane & 15)];
  f32x4 acc0 = {0.f, 0.f, 0.f, 0.f};
  f32x4 acc1 = {0.f, 0.f, 0.f, 0.f};
  const int jb = (lane >> 4) * 8;

  for (int chunk = 0; chunk < 8; ++chunk) {
    __syncthreads();   // WAR on w_s (and covers g_s first time)
    #pragma unroll
    for (int sg = 0; sg < 4; ++sg) {
      int seg = wid * 4 + sg;            // 0..31 : arr*16 + h*8 + ksl
      int arr = seg >> 4, h = (seg >> 3) & 1, ksl = seg & 7;
      const u32* src = (arr ? Wlo : Whi) +
          (((size_t)h * 64 + chunk * 8 + ksl) * 64 + lane) * 4;
      *(uint4*)&w_s[seg * 256 + lane * 4] = *(const uint4*)src;
    }
    __syncthreads();
    #pragma unroll
    for (int ksl = 0; ksl < 8; ++ksl) {
      const float* gp = &g_s[chunk * 256 + ksl * 32 + jb];
      float4 gja = *(const float4*)gp;
      float4 gjb = *(const float4*)(gp + 4);
      float gv[8] = {gja.x, gja.y, gja.z, gja.w, gjb.x, gjb.y, gjb.z, gjb.w};
      float kv[8];
      #pragma unroll
      for (int q = 0; q < 8; ++q) {
        float d = gi - gv[q];
        kv[q] = fast_exp2(d * d * CEXP);
      }
      U16 ah, al;
      split8(kv, ah, al);
      U16 w0h, w1h, w0l, w1l;
      w0h.u = *(const uint4*)&w_s[(ksl) * 256 + lane * 4];
      w1h.u = *(const uint4*)&w_s[(8 + ksl) * 256 + lane * 4];
      w0l.u = *(const uint4*)&w_s[(16 + ksl) * 256 + lane * 4];
      w1l.u = *(const uint4*)&w_s[(24 + ksl) * 256 + lane * 4];
      acc0 = __builtin_amdgcn_mfma_f32_16x16x32_bf16(ah.v, w0h.v, acc0, 0, 0, 0);
      acc0 = __builtin_amdgcn_mfma_f32_16x16x32_bf16(al.v, w0h.v, acc0, 0, 0, 0);
      acc0 = __builtin_amdgcn_mfma_f32_16x16x32_bf16(ah.v, w0l.v, acc0, 0, 0, 0);
      acc1 = __builtin_amdgcn_mfma_f32_16x16x32_bf16(ah.v, w1h.v, acc1, 0, 0, 0);
      acc1 = __builtin_amdgcn_mfma_f32_16x16x32_bf16(al.v, w1h.v, acc1, 0, 0, 0);
      acc1 = __builtin_amdgcn_mfma_f32_16x16x32_bf16(ah.v, w1l.v, acc1, 0, 0, 0);
    }
  }
  // epilogue: gf = gv + brbf + emb gather; write frag-linear bf16 hi/lo
  const int idx = (int)x[(size_t)b * XS + Gg + Dd];
  const int eloc = lane & 15, quad = lane >> 4;
  const int ks = i0w >> 5;
  const int lp = (2 * ((i0w >> 4) & 1) + (quad >> 1)) * 16 + eloc;
  const int hs = quad & 1;
  #pragma unroll
  for (int hb = 0; hb < 2; ++hb) {
    const int e = hb * 16 + eloc;
    const float bias = brbf[e];
    f32x4 a = hb ? acc1 : acc0;
    float v[4];
    #pragma unroll
    for (int r = 0; r < 4; ++r) {
      int i = i0w + quad * 4 + r;
      int t = table[idx * Gg + i];
      v[r] = a[r] + bias + emb[t * 32 + e];
    }
    size_t off = ((size_t)((b * 2 + hb) * 64 + ks) * 64 + lp) * 4 + hs * 2;
    Ahi[off]     = pk2(v[0], v[1]);
    Ahi[off + 1] = pk2(v[2], v[3]);
    Alo[off]     = pk2(v[0] - bftrunc(v[0]), v[1] - bftrunc(v[1]));
    Alo[off + 1] = pk2(v[2] - bftrunc(v[2]), v[3] - bftrunc(v[3]));
  }
}

// ---------------- K2: gene GEMM 512x1024x2048, split-bf16 MFMA ------------
// grid (16 n-tiles, 8 m-tiles, 4 k-chunks), 256 thr = 4 waves (2x2).
__global__ __launch_bounds__(256) void k_mm(const u32* __restrict__ Ahi,
                                            const u32* __restrict__ Alo,
                                            const u32* __restrict__ Bhi,
                                            const u32* __restrict__ Blo,
                                            float* __restrict__ part) {
  __shared__ u32 s_mm[8192];   // A segs 0..15, B segs 16..31
  const int tid = threadIdx.x;
  const int lane = tid & 63, wid = tid >> 6;
  const int wm = wid >> 1, wn = wid & 1;
  const int bx = blockIdx.x, by = blockIdx.y, kc = blockIdx.z;
  f32x4 acc00 = {0.f,0.f,0.f,0.f}, acc01 = {0.f,0.f,0.f,0.f};
  f32x4 acc10 = {0.f,0.f,0.f,0.f}, acc11 = {0.f,0.f,0.f,0.f};

  for (int stage = 0; stage < 8; ++stage) {
    const int ks0 = kc * 16 + stage * 2;
    __syncthreads();
    #pragma unroll
    for (int sg = 0; sg < 8; ++sg) {
      int seg = wid * 8 + sg;        // aorb*16 + hl*8 + idx4*2 + ksl
      int aorb = seg >> 4;
      int s2 = seg & 15;
      int hl = s2 >> 3, idx4 = (s2 >> 1) & 3, ksl = s2 & 1;
      const u32* src;
      if (aorb == 0)
        src = (hl ? Alo : Ahi) + (((size_t)(by * 4 + idx4) * 64 + ks0 + ksl) * 64 + lane) * 4;
      else
        src = (hl ? Blo : Bhi) + (((size_t)(bx * 4 + idx4) * 64 + ks0 + ksl) * 64 + lane) * 4;
      *(uint4*)&s_mm[seg * 256 + lane * 4] = *(const uint4*)src;
    }
    __syncthreads();
    #pragma unroll
    for (int ksl = 0; ksl < 2; ++ksl) {
      U16 a0h, a1h, a0l, a1l, b0h, b1h, b0l, b1l;
      a0h.u = *(const uint4*)&s_mm[((wm * 2 + 0) * 2 + ksl) * 256 + lane * 4];
      a1h.u = *(const uint4*)&s_mm[((wm * 2 + 1) * 2 + ksl) * 256 + lane * 4];
      a0l.u = *(const uint4*)&s_mm[(8 * 1 + (wm * 2 + 0) * 2 + ksl) * 256 + lane * 4 + 8 * 0];
      a0l.u = *(const uint4*)&s_mm[(8 + (wm * 2 + 0) * 2 + ksl) * 256 + lane * 4];
      a1l.u = *(const uint4*)&s_mm[(8 + (wm * 2 + 1) * 2 + ksl) * 256 + lane * 4];
      b0h.u = *(const uint4*)&s_mm[(16 + (wn * 2 + 0) * 2 + ksl) * 256 + lane * 4];
      b1h.u = *(const uint4*)&s_mm[(16 + (wn * 2 + 1) * 2 + ksl) * 256 + lane * 4];
      b0l.u = *(const uint4*)&s_mm[(24 + (wn * 2 + 0) * 2 + ksl) * 256 + lane * 4];
      b1l.u = *(const uint4*)&s_mm[(24 + (wn * 2 + 1) * 2 + ksl) * 256 + lane * 4];
      acc00 = __builtin_amdgcn_mfma_f32_16x16x32_bf16(a0h.v, b0h.v, acc00, 0, 0, 0);
      acc00 = __builtin_amdgcn_mfma_f32_16x16x32_bf16(a0l.v, b0h.v, acc00, 0, 0, 0);
      acc00 = __builtin_amdgcn_mfma_f32_16x16x32_bf16(a0h.v, b0l.v, acc00, 0, 0, 0);
      acc01 = __builtin_amdgcn_mfma_f32_16x16x32_bf16(a0h.v, b1h.v, acc01, 0, 0, 0);
      acc01 = __builtin_amdgcn_mfma_f32_16x16x32_bf16(a0l.v, b1h.v, acc01, 0, 0, 0);
      acc01 = __builtin_amdgcn_mfma_f32_16x16x32_bf16(a0h.v, b1l.v, acc01, 0, 0, 0);
      acc10 = __builtin_amdgcn_mfma_f32_16x16x32_bf16(a1h.v, b0h.v, acc10, 0, 0, 0);
      acc10 = __builtin_amdgcn_mfma_f32_16x16x32_bf16(a1l.v, b0h.v, acc10, 0, 0, 0);
      acc10 = __builtin_amdgcn_mfma_f32_16x16x32_bf16(a1h.v, b0l.v, acc10, 0, 0, 0);
      acc11 = __builtin_amdgcn_mfma_f32_16x16x32_bf16(a1h.v, b1h.v, acc11, 0, 0, 0);
      acc11 = __builtin_amdgcn_mfma_f32_16x16x32_bf16(a1l.v, b1h.v, acc11, 0, 0, 0);
      acc11 = __builtin_amdgcn_mfma_f32_16x16x32_bf16(a1h.v, b1l.v, acc11, 0, 0, 0);
    }
  }
  const int quad = lane >> 4, nl = lane & 15;
  #pragma unroll
  for (int mtl = 0; mtl < 2; ++mtl) {
    #pragma unroll
    for (int nfl = 0; nfl < 2; ++nfl) {
      f32x4 a = mtl ? (nfl ? acc11 : acc10) : (nfl ? acc01 : acc00);
      #pragma unroll
      for (int r = 0; r < 4; ++r) {
        int m = by * 64 + wm * 32 + mtl * 16 + quad * 4 + r;
        int n = bx * 64 + wn * 32 + nfl * 16 + nl;
        part[(size_t)kc * 524288 + (size_t)m * 1024 + n] = a[r];
      }
    }
  }
}

// ---------------- K3: reduce K-chunks + bias -> gene_out (l,b,e,gs) ------
__global__ __launch_bounds__(256) void k_gout(const float* __restrict__ part,
                                              const float* __restrict__ bdg,
                                              float* __restrict__ gout) {
  int flat = blockIdx.x * 256 + threadIdx.x;   // 524288
  int m = flat >> 10, n = flat & 1023;
  float v = part[flat] + part[524288 + flat] + part[2 * 524288 + flat] +
            part[3 * 524288 + flat] + bdg[n];
  int l = n >> 6, kgs = n & 63, b = m >> 5, e = m & 31;
  gout[(((size_t)l * Bb + b) * 32 + e) * 64 + kgs] = v;
}

// ---------------- batchnorm over 512 threads, 6 channels -----------------
__device__ inline void bn512(float* v, int wv, int lane,
                             float (*r1)[6], float (*r2)[6]) {
  float s[6], q[6];
  #pragma unroll
  for (int c = 0; c < 6; ++c) {
    float a = v[c];
    s[c] = wred(a);
    q[c] = wred(a * a);
  }
  __syncthreads();
  if (lane == 0) {
    #pragma unroll
    for (int c = 0; c < 6; ++c) { r1[wv][c] = s[c]; r2[wv][c] = q[c]; }
  }
  __syncthreads();
  #pragma unroll
  for (int c = 0; c < 6; ++c) {
    float S = 0.f, Q = 0.f;
    #pragma unroll
    for (int w = 0; w < 8; ++w) { S += r1[w][c]; Q += r2[w][c]; }
    float m  = S * (1.0f / 512.0f);
    float va = Q * (1.0f / 512.0f) - m * m;
    v[c] = (v[c] - m) * rsqrtf(va + EPSf);
  }
}

// ---------------- K4/K5: _term 3d part ------------------------------------
template <int IN, int MODE>
__global__ __launch_bounds__(512) void k_term(const float* __restrict__ gin,
                                              const float* __restrict__ W1,
                                              const float* __restrict__ b1,
                                              const float* __restrict__ Wc,
                                              const float* __restrict__ bc,
                                              float* __restrict__ outp) {
  const int l = blockIdx.x, tid = threadIdx.x;
  const int wv = tid >> 6, lane = tid & 63;
  __shared__ float r1[8][6], r2[8][6];
  const float* ci = gin + ((size_t)l * 512 + tid) * IN;
  float cv[IN];
  #pragma unroll
  for (int q = 0; q < IN / 4; ++q)
    *(float4*)&cv[q * 4] = ((const float4*)ci)[q];
  const float* w1 = W1 + l * 6 * IN;
  float h[6];
  #pragma unroll
  for (int hh = 0; hh < 6; ++hh) {
    float s = b1[l * 6 + hh];
    #pragma unroll
    for (int i = 0; i < IN; ++i) s = fmaf(cv[i], w1[hh * IN + i], s);
    h[hh] = s;
  }
  bn512(h, wv, lane, r1, r2);
  float c[6];
  #pragma unroll
  for (int k = 0; k < 6; ++k) {
    float s = bc[l * 6 + k];
    #pragma unroll
    for (int hh = 0; hh < 6; ++hh) s = fmaf(h[hh], Wc[l * 36 + k * 6 + hh], s);
    c[k] = s;
  }
  bn512(c, wv, lane, r1, r2);
  if (MODE == 0) {
    float* o = outp + (((size_t)(l >> 2) * 512 + tid) * 24 + (l & 3) * 6);
    #pragma unroll
    for (int k = 0; k < 6; ++k) o[k] = c[k];
  } else {
    float* o = outp + ((size_t)tid * 24 + l * 6);
    #pragma unroll
    for (int k = 0; k < 6; ++k) o[k] = c[k];
  }
}

// ---------------- K6: root term -------------------------------------------
__global__ __launch_bounds__(512) void k_root(const float* __restrict__ rootin,
                                              const float* __restrict__ Wr1,
                                              const float* __restrict__ br1,
                                              const float* __restrict__ Wrc,
                                              const float* __restrict__ brc,
                                              const float* __restrict__ Wrd,
                                              const float* __restrict__ brd,
                                              float* __restrict__ r2d) {
  const int tid = threadIdx.x;
  const int wv = tid >> 6, lane = tid & 63;
  __shared__ float r1[8][6], r2[8][6];
  const float* ci = rootin + (size_t)tid * 24;
  float cv[24];
  #pragma unroll
  for (int q = 0; q < 6; ++q) *(float4*)&cv[q * 4] = ((const float4*)ci)[q];
  float h[6];
  #pragma unroll
  for (int hh = 0; hh < 6; ++hh) {
    float s = br1[hh];
    #pragma unroll
    for (int i = 0; i < 24; ++i) s = fmaf(cv[i], Wr1[hh * 24 + i], s);
    h[hh] = s;
  }
  bn512(h, wv, lane, r1, r2);
  float c[6];
  #pragma unroll
  for (int k = 0; k < 6; ++k) {
    float s = brc[k];
    #pragma unroll
    for (int hh = 0; hh < 6; ++hh) s = fmaf(h[hh], Wrc[k * 6 + hh], s);
    c[k] = s;
  }
  bn512(c, wv, lane, r1, r2);
  float mv = (c[0] + c[1] + c[2] + c[3] + c[4] + c[5]) * (1.0f / 6.0f);
  __shared__ float shm[512];
  shm[tid] = mv;
  __syncthreads();
  __shared__ float st[96];
  if (tid < 96) {
    int b = tid / 6, hh = tid % 6;
    float s = brd[hh];
    #pragma unroll
    for (int e = 0; e < 32; ++e) s = fmaf(shm[b * 32 + e], Wrd[hh * 32 + e], s);
    st[tid] = tanhf(s);
  }
  __syncthreads();
  if (tid < 6) {
    float S = 0.f, Q = 0.f;
    for (int b = 0; b < 16; ++b) { float v = st[b * 6 + tid]; S += v; Q += v * v; }
    float m = S * (1.0f / 16.0f), va = Q * (1.0f / 16.0f) - m * m;
    float iv = rsqrtf(va + EPSf);
    for (int b = 0; b < 16; ++b) r2d[b * 6 + tid] = (st[b * 6 + tid] - m) * iv;
  }
}

// ---------------- K7: drug layer 1 -----------------------------------------
__global__ __launch_bounds__(256) void k_drug1(const float* __restrict__ x,
                                               const float* __restrict__ Wd1,
                                               const float* __restrict__ bd1,
                                               float* __restrict__ d1) {
  const int c = blockIdx.x;        // 0..99
  const int tid = threadIdx.x;
  const int b = tid >> 4, li = tid & 15;
  const float* xb = x + (size_t)b * XS + Gg;
  const float* w = Wd1 + (size_t)c * 2048;
  float s = 0.f;
  for (int k = li; k < 2048; k += 16) s = fmaf(xb[k], w[k], s);
  __shared__ float red[256];
  red[tid] = s;
  __syncthreads();
  __shared__ float y[16];
  if (li == 0) {
    float t = 0.f;
    #pragma unroll
    for (int q = 0; q < 16; ++q) t += red[b * 16 + q];
    y[b] = tanhf(t + bd1[c]);
  }
  __syncthreads();
  if (tid < 16) {
    float S = 0.f, Q = 0.f;
    #pragma unroll
    for (int bb = 0; bb < 16; ++bb) { float v = y[bb]; S += v; Q += v * v; }
    float m = S * (1.0f / 16.0f), va = Q * (1.0f / 16.0f) - m * m;
    d1[tid * 100 + c] = (y[tid] - m) * rsqrtf(va + EPSf);
  }
}

// ---------------- K8: drug layers 2-3 + final head -------------------------
__global__ __launch_bounds__(512) void k_final(const float* __restrict__ d1,
                                               const float* __restrict__ r2d,
                                               const float* __restrict__ Wd2,
                                               const float* __restrict__ bd2,
                                               const float* __restrict__ Wd3,
                                               const float* __restrict__ bd3,
                                               const float* __restrict__ Wf,
                                               const float* __restrict__ bf,
                                               const float* __restrict__ Wfa,
                                               const float* __restrict__ bfa,
                                               const float* __restrict__ Wfo,
                                               const float* __restrict__ bfo,
                                               float* __restrict__ out) {
  const int tid = threadIdx.x;
  __shared__ float s2[800], mu2[50], iv2[50];
  for (int u = tid; u < 800; u += 512) {
    int b = u / 50, c = u % 50;
    float s = bd2[c];
    for (int k = 0; k < 100; ++k) s = fmaf(d1[b * 100 + k], Wd2[c * 100 + k], s);
    s2[u] = tanhf(s);
  }
  __syncthreads();
  if (tid < 50) {
    float S = 0.f, Q = 0.f;
    #pragma unroll
    for (int b = 0; b < 16; ++b) { float v = s2[b * 50 + tid]; S += v; Q += v * v; }
    float m = S * (1.0f / 16.0f), va = Q * (1.0f / 16.0f) - m * m;
    mu2[tid] = m; iv2[tid] = rsqrtf(va + EPSf);
  }
  __syncthreads();
  __shared__ float s3[96], mu3[6], iv3[6];
  if (tid < 96) {
    int b = tid / 6, c = tid % 6;
    float s = bd3[c];
    for (int k = 0; k < 50; ++k)
      s = fmaf((s2[b * 50 + k] - mu2[k]) * iv2[k], Wd3[c * 50 + k], s);
    s3[tid] = tanhf(s);
  }
  __syncthreads();
  if (tid < 6) {
    float S = 0.f, Q = 0.f;
    #pragma unroll
    for (int b = 0; b < 16; ++b) { float v = s3[b * 6 + tid]; S += v; Q += v * v; }
    float m = S * (1.0f / 16.0f), va = Q * (1.0f / 16.0f) - m * m;
    mu3[tid] = m; iv3[tid] = rsqrtf(va + EPSf);
  }
  __syncthreads();
  __shared__ float sf[96], muf[6], ivf[6];
  if (tid < 96) {
    int b = tid / 6, c = tid % 6;
    float s = bf[c];
    #pragma unroll
    for (int q = 0; q < 6; ++q) s = fmaf(r2d[b * 6 + q], Wf[c * 12 + q], s);
    #pragma unroll
    for (int q = 0; q < 6; ++q)
      s = fmaf((s3[b * 6 + q] - mu3[q]) * iv3[q], Wf[c * 12 + 6 + q], s);
    sf[tid] = tanhf(s);
  }
  __syncthreads();
  if (tid < 6) {
    float S = 0.f, Q = 0.f;
    #pragma unroll
    for (int b = 0; b < 16; ++b) { float v = sf[b * 6 + tid]; S += v; Q += v * v; }
    float m = S * (1.0f / 16.0f), va = Q * (1.0f / 16.0f) - m * m;
    muf[tid] = m; ivf[tid] = rsqrtf(va + EPSf);
  }
  __syncthreads();
  if (tid < 16) {
    float s = bfa[0];
    #pragma unroll
    for (int q = 0; q < 6; ++q)
      s = fmaf((sf[tid * 6 + q] - muf[q]) * ivf[q], Wfa[q], s);
    float a = tanhf(s);
    out[tid] = a * Wfo[0] + bfo[0];
  }
}

extern "C" void kernel_launch(void* const* d_in, const int* in_sizes, int n_in,
                              void* d_out, int out_size, void* d_ws, size_t ws_size,
                              hipStream_t stream) {
  const float* x     = (const float*)d_in[0];
  const int*   table = (const int*)d_in[1];
  const float* Wrbf  = (const float*)d_in[2];
  const float* brbf  = (const float*)d_in[3];
  const float* emb   = (const float*)d_in[4];
  const float* Wdg   = (const float*)d_in[5];
  const float* bdg   = (const float*)d_in[6];
  const float* Wl1   = (const float*)d_in[7];
  const float* bl1   = (const float*)d_in[8];
  const float* Wlc   = (const float*)d_in[9];
  const float* blc   = (const float*)d_in[10];
  const float* Wm1   = (const float*)d_in[13];
  const float* bm1   = (const float*)d_in[14];
  const float* Wmc   = (const float*)d_in[15];
  const float* bmc   = (const float*)d_in[16];
  const float* Wr1   = (const float*)d_in[19];
  const float* br1   = (const float*)d_in[20];
  const float* Wrc   = (const float*)d_in[21];
  const float* brc   = (const float*)d_in[22];
  const float* Wrd   = (const float*)d_in[23];
  const float* brd   = (const float*)d_in[24];
  const float* Wd1   = (const float*)d_in[25];
  const float* bd1   = (const float*)d_in[26];
  const float* Wd2   = (const float*)d_in[27];
  const float* bd2   = (const float*)d_in[28];
  const float* Wd3   = (const float*)d_in[29];
  const float* bd3   = (const float*)d_in[30];
  const float* Wf    = (const float*)d_in[31];
  const float* bf    = (const float*)d_in[32];
  const float* Wfa   = (const float*)d_in[33];
  const float* bfa   = (const float*)d_in[34];
  const float* Wfo   = (const float*)d_in[35];
  const float* bfo   = (const float*)d_in[36];
  float* out = (float*)d_out;

  u32* Rhi = (u32*)d_ws;                   // 32768
  u32* Rlo = Rhi + 32768;                  // 32768
  u32* Dhi = Rlo + 32768;                  // 1048576
  u32* Dlo = Dhi + 1048576;                // 1048576
  u32* Ahi = Dlo + 1048576;                // 524288
  u32* Alo = Ahi + 524288;                 // 524288
  float* partB = (float*)(Alo + 524288);   // 4 * 524288
  float* gout  = partB + 4 * 524288;       // 524288
  float* midin = gout + 524288;            // 49152
  float* rootin= midin + 49152;            // 12288
  float* r2d   = rootin + 12288;           // 96
  float* d1    = r2d + 96;                 // 1600

  hipLaunchKernelGGL(k_split, dim3(1056),      dim3(256), 0, stream, Wrbf, Wdg, Rhi, Rlo, Dhi, Dlo);
  hipLaunchKernelGGL(k_rbf,   dim3(16, 16),    dim3(512), 0, stream, x, Rhi, Rlo, table, emb, brbf, Ahi, Alo);
  hipLaunchKernelGGL(k_mm,    dim3(16, 8, 4),  dim3(256), 0, stream, Ahi, Alo, Dhi, Dlo, partB);
  hipLaunchKernelGGL(k_gout,  dim3(2048),      dim3(256), 0, stream, partB, bdg, gout);
  hipLaunchKernelGGL((k_term<64, 0>), dim3(16), dim3(512), 0, stream, gout, Wl1, bl1, Wlc, blc, midin);
  hipLaunchKernelGGL((k_term<24, 1>), dim3(4),  dim3(512), 0, stream, midin, Wm1, bm1, Wmc, bmc, rootin);
  hipLaunchKernelGGL(k_root,  dim3(1),   dim3(512), 0, stream, rootin, Wr1, br1, Wrc, brc, Wrd, brd, r2d);
  hipLaunchKernelGGL(k_drug1, dim3(100), dim3(256), 0, stream, x, Wd1, bd1, d1);
  hipLaunchKernelGGL(k_final, dim3(1),   dim3(512), 0, stream, d1, r2d, Wd2, bd2, Wd3, bd3,
                     Wf, bf, Wfa, bfa, Wfo, bfo, out);
}

// Round 3
// 125.031 us; speedup vs baseline: 1.9156x; 1.1848x over previous
//
#include <hip/hip_runtime.h>
#include <hip/hip_bf16.h>

// Sizes
#define Bb 16
#define Gg 2048
#define Dd 2048
#define XS 4097   // G + D + 1
#define EPSf 1e-5f
#define CEXP (-0.72134752044448170368f)   // -gamma * log2(e), gamma = 0.5

typedef unsigned int u32;
typedef __attribute__((ext_vector_type(8))) short bf16x8;
typedef __attribute__((ext_vector_type(4))) float f32x4;

union U16 { uint4 u; bf16x8 v; };

__device__ inline float fast_exp2(float x) {
#if __has_builtin(__builtin_amdgcn_exp2f)
  return __builtin_amdgcn_exp2f(x);
#else
  return exp2f(x);
#endif
}

// pack two f32 into one u32 of 2 bf16 (truncation): low half from a, high from b
__device__ inline u32 pk2(float a, float b) {
  return __builtin_amdgcn_perm(__float_as_uint(b), __float_as_uint(a), 0x07060302u);
}
__device__ inline float bftrunc(float a) {
  return __uint_as_float(__float_as_uint(a) & 0xFFFF0000u);
}

// split 8 floats into hi/lo bf16x8 fragments
__device__ inline void split8(const float* f, U16& hi, U16& lo) {
  u32 h[4], l[4];
  #pragma unroll
  for (int p = 0; p < 4; ++p) {
    float a = f[2 * p], b = f[2 * p + 1];
    h[p] = pk2(a, b);
    l[p] = pk2(a - bftrunc(a), b - bftrunc(b));
  }
  hi.u = make_uint4(h[0], h[1], h[2], h[3]);
  lo.u = make_uint4(l[0], l[1], l[2], l[3]);
}

__device__ inline float wred(float v) {
  #pragma unroll
  for (int o = 32; o > 0; o >>= 1) v += __shfl_xor(v, o, 64);
  return v;
}

// ---------------- K0: split weights into MFMA-frag-linear bf16 hi/lo ------
__global__ __launch_bounds__(256) void k_split(const float* __restrict__ Wrbf,
                                               const float* __restrict__ Wdg,
                                               u32* __restrict__ Rhi, u32* __restrict__ Rlo,
                                               u32* __restrict__ Dhi, u32* __restrict__ Dlo) {
  int c = blockIdx.x * 256 + threadIdx.x;   // 270336 total
  const float* src;
  u32 *dhi, *dlo;
  if (c < 8192) {
    int h = c >> 12, ks = (c >> 6) & 63, l = c & 63;
    src = Wrbf + (h * 16 + (l & 15)) * Gg + ks * 32 + (l >> 4) * 8;
    dhi = Rhi + (size_t)c * 4; dlo = Rlo + (size_t)c * 4;
  } else {
    int cc = c - 8192;
    int nf = cc >> 12, ks = (cc >> 6) & 63, l = cc & 63;
    src = Wdg + (size_t)(nf * 16 + (l & 15)) * Gg + ks * 32 + (l >> 4) * 8;
    dhi = Dhi + (size_t)cc * 4; dlo = Dlo + (size_t)cc * 4;
  }
  float4 f0 = *(const float4*)src;
  float4 f1 = *(const float4*)(src + 4);
  float f[8] = {f0.x, f0.y, f0.z, f0.w, f1.x, f1.y, f1.z, f1.w};
  U16 hi, lo;
  split8(f, hi, lo);
  *(uint4*)dhi = hi.u;
  *(uint4*)dlo = lo.u;
}

// ---------------- K1: fused RBF einsum via MFMA; emits gf frag-linear -----
__global__ __launch_bounds__(512) void k_rbf(const float* __restrict__ x,
                                             const u32* __restrict__ Whi,
                                             const u32* __restrict__ Wlo,
                                             const int* __restrict__ table,
                                             const float* __restrict__ emb,
                                             const float* __restrict__ brbf,
                                             u32* __restrict__ Ahi,
                                             u32* __restrict__ Alo) {
  __shared__ float g_s[2048];
  __shared__ u32 w_s[8192];   // 32 segs x 256 u32 (1KB each)
  const int tid = threadIdx.x;
  const int lane = tid & 63, wid = tid >> 6;
  const int b = blockIdx.y;
  const int i0w = blockIdx.x * 128 + wid * 16;
  #pragma unroll
  for (int q = 0; q < 4; ++q) g_s[tid * 4 + q] = x[(size_t)b * XS + tid * 4 + q];
  const float gi = x[(size_t)b * XS + i0w + (lane & 15)];
  f32x4 acc0 = {0.f, 0.f, 0.f, 0.f};
  f32x4 acc1 = {0.f, 0.f, 0.f, 0.f};
  const int jb = (lane >> 4) * 8;

  for (int chunk = 0; chunk < 8; ++chunk) {
    __syncthreads();
    #pragma unroll
    for (int sg = 0; sg < 4; ++sg) {
      int seg = wid * 4 + sg;            // 0..31 : arr*16 + h*8 + ksl
      int arr = seg >> 4, h = (seg >> 3) & 1, ksl = seg & 7;
      const u32* src = (arr ? Wlo : Whi) +
          (((size_t)h * 64 + chunk * 8 + ksl) * 64 + lane) * 4;
      *(uint4*)&w_s[seg * 256 + lane * 4] = *(const uint4*)src;
    }
    __syncthreads();
    #pragma unroll
    for (int ksl = 0; ksl < 8; ++ksl) {
      const float* gp = &g_s[chunk * 256 + ksl * 32 + jb];
      float4 gja = *(const float4*)gp;
      float4 gjb = *(const float4*)(gp + 4);
      float gv[8] = {gja.x, gja.y, gja.z, gja.w, gjb.x, gjb.y, gjb.z, gjb.w};
      float kv[8];
      #pragma unroll
      for (int q = 0; q < 8; ++q) {
        float d = gi - gv[q];
        kv[q] = fast_exp2(d * d * CEXP);
      }
      U16 ah, al;
      split8(kv, ah, al);
      U16 w0h, w1h, w0l, w1l;
      w0h.u = *(const uint4*)&w_s[(ksl) * 256 + lane * 4];
      w1h.u = *(const uint4*)&w_s[(8 + ksl) * 256 + lane * 4];
      w0l.u = *(const uint4*)&w_s[(16 + ksl) * 256 + lane * 4];
      w1l.u = *(const uint4*)&w_s[(24 + ksl) * 256 + lane * 4];
      acc0 = __builtin_amdgcn_mfma_f32_16x16x32_bf16(ah.v, w0h.v, acc0, 0, 0, 0);
      acc0 = __builtin_amdgcn_mfma_f32_16x16x32_bf16(al.v, w0h.v, acc0, 0, 0, 0);
      acc0 = __builtin_amdgcn_mfma_f32_16x16x32_bf16(ah.v, w0l.v, acc0, 0, 0, 0);
      acc1 = __builtin_amdgcn_mfma_f32_16x16x32_bf16(ah.v, w1h.v, acc1, 0, 0, 0);
      acc1 = __builtin_amdgcn_mfma_f32_16x16x32_bf16(al.v, w1h.v, acc1, 0, 0, 0);
      acc1 = __builtin_amdgcn_mfma_f32_16x16x32_bf16(ah.v, w1l.v, acc1, 0, 0, 0);
    }
  }
  // epilogue: gf = gv + brbf + emb gather; write frag-linear bf16 hi/lo
  const int idx = (int)x[(size_t)b * XS + Gg + Dd];
  const int eloc = lane & 15, quad = lane >> 4;
  const int ks = i0w >> 5;
  const int lp = (2 * ((i0w >> 4) & 1) + (quad >> 1)) * 16 + eloc;
  const int hs = quad & 1;
  #pragma unroll
  for (int hb = 0; hb < 2; ++hb) {
    const int e = hb * 16 + eloc;
    const float bias = brbf[e];
    f32x4 a = hb ? acc1 : acc0;
    float v[4];
    #pragma unroll
    for (int r = 0; r < 4; ++r) {
      int i = i0w + quad * 4 + r;
      int t = table[idx * Gg + i];
      v[r] = a[r] + bias + emb[t * 32 + e];
    }
    size_t off = ((size_t)((b * 2 + hb) * 64 + ks) * 64 + lp) * 4 + hs * 2;
    Ahi[off]     = pk2(v[0], v[1]);
    Ahi[off + 1] = pk2(v[2], v[3]);
    Alo[off]     = pk2(v[0] - bftrunc(v[0]), v[1] - bftrunc(v[1]));
    Alo[off + 1] = pk2(v[2] - bftrunc(v[2]), v[3] - bftrunc(v[3]));
  }
}

// ---------------- K2: gene GEMM 512x1024x2048, split-bf16 MFMA ------------
// 256 blocks (1/CU): BM=64 (by), BN=128 (bx), kc=4 (K=512 each).
// XCD swizzle: blocks sharing a (bx,kc) B-panel land on the same XCD.
// partB layout: [kc][n][m] (column-major) for coalesced epilogue + consumer.
__global__ __launch_bounds__(256) void k_mm(const u32* __restrict__ Ahi,
                                            const u32* __restrict__ Alo,
                                            const u32* __restrict__ Bhi,
                                            const u32* __restrict__ Blo,
                                            float* __restrict__ part) {
  __shared__ u32 s_mm[6144];   // 24 segs x 1KB
  const int tid = threadIdx.x;
  const int lane = tid & 63, wid = tid >> 6;
  const int id = blockIdx.x;
  const int pl = id & 7, by = (id >> 3) & 7, ph = id >> 6;
  const int p = ph * 8 + pl;
  const int bx = p >> 2, kc = p & 3;
  const int wm = wid >> 1, wn = wid & 1;
  f32x4 acc[2][4];
  #pragma unroll
  for (int mf = 0; mf < 2; ++mf)
    #pragma unroll
    for (int nf = 0; nf < 4; ++nf) acc[mf][nf] = (f32x4){0.f, 0.f, 0.f, 0.f};

  for (int stage = 0; stage < 16; ++stage) {
    const int ks = kc * 16 + stage;
    __syncthreads();
    #pragma unroll
    for (int q = 0; q < 6; ++q) {
      int seg = wid * 6 + q;     // 0..23
      const u32* src;
      if (seg < 8) {             // A: hl(2) x mf(4)
        int hl = seg >> 2, mf = seg & 3;
        src = (hl ? Alo : Ahi) + (((size_t)(by * 4 + mf) * 64 + ks) * 64 + lane) * 4;
      } else {                   // B: hl(2) x nf(8)
        int t = seg - 8, hl = t >> 3, nf = t & 7;
        src = (hl ? Blo : Bhi) + (((size_t)(bx * 8 + nf) * 64 + ks) * 64 + lane) * 4;
      }
      *(uint4*)&s_mm[seg * 256 + lane * 4] = *(const uint4*)src;
    }
    __syncthreads();
    U16 ah[2], al[2], bh[4], bl[4];
    #pragma unroll
    for (int mf = 0; mf < 2; ++mf) {
      ah[mf].u = *(const uint4*)&s_mm[(0 + wm * 2 + mf) * 256 + lane * 4];
      al[mf].u = *(const uint4*)&s_mm[(4 + wm * 2 + mf) * 256 + lane * 4];
    }
    #pragma unroll
    for (int nf = 0; nf < 4; ++nf) {
      bh[nf].u = *(const uint4*)&s_mm[(8 + wn * 4 + nf) * 256 + lane * 4];
      bl[nf].u = *(const uint4*)&s_mm[(16 + wn * 4 + nf) * 256 + lane * 4];
    }
    #pragma unroll
    for (int mf = 0; mf < 2; ++mf) {
      #pragma unroll
      for (int nf = 0; nf < 4; ++nf) {
        acc[mf][nf] = __builtin_amdgcn_mfma_f32_16x16x32_bf16(ah[mf].v, bh[nf].v, acc[mf][nf], 0, 0, 0);
        acc[mf][nf] = __builtin_amdgcn_mfma_f32_16x16x32_bf16(al[mf].v, bh[nf].v, acc[mf][nf], 0, 0, 0);
        acc[mf][nf] = __builtin_amdgcn_mfma_f32_16x16x32_bf16(ah[mf].v, bl[nf].v, acc[mf][nf], 0, 0, 0);
      }
    }
  }
  const int quad = lane >> 4, nl = lane & 15;
  #pragma unroll
  for (int mf = 0; mf < 2; ++mf) {
    #pragma unroll
    for (int nf = 0; nf < 4; ++nf) {
      int n  = bx * 128 + wn * 64 + nf * 16 + nl;
      int m0 = by * 64 + wm * 32 + mf * 16 + quad * 4;
      float4 st = make_float4(acc[mf][nf][0], acc[mf][nf][1], acc[mf][nf][2], acc[mf][nf][3]);
      *(float4*)&part[(size_t)kc * 524288 + (size_t)n * 512 + m0] = st;
    }
  }
}

// ---------------- batchnorm over 512 threads, 6 channels -----------------
__device__ inline void bn512(float* v, int wv, int lane,
                             float (*r1)[6], float (*r2)[6]) {
  float s[6], q[6];
  #pragma unroll
  for (int c = 0; c < 6; ++c) {
    float a = v[c];
    s[c] = wred(a);
    q[c] = wred(a * a);
  }
  __syncthreads();
  if (lane == 0) {
    #pragma unroll
    for (int c = 0; c < 6; ++c) { r1[wv][c] = s[c]; r2[wv][c] = q[c]; }
  }
  __syncthreads();
  #pragma unroll
  for (int c = 0; c < 6; ++c) {
    float S = 0.f, Q = 0.f;
    #pragma unroll
    for (int w = 0; w < 8; ++w) { S += r1[w][c]; Q += r2[w][c]; }
    float m  = S * (1.0f / 512.0f);
    float va = Q * (1.0f / 512.0f) - m * m;
    v[c] = (v[c] - m) * rsqrtf(va + EPSf);
  }
}

// ---------------- K3: leaf term; reads partB directly (fused reduce+bias) -
__global__ __launch_bounds__(512) void k_leaf(const float* __restrict__ part,
                                              const float* __restrict__ bdg,
                                              const float* __restrict__ W1,
                                              const float* __restrict__ b1,
                                              const float* __restrict__ Wc,
                                              const float* __restrict__ bc,
                                              float* __restrict__ outp) {
  const int l = blockIdx.x, tid = threadIdx.x;   // tid = b*32+e
  const int wv = tid >> 6, lane = tid & 63;
  __shared__ float r1[8][6], r2[8][6];
  float cv[64];
  #pragma unroll
  for (int i = 0; i < 64; ++i) {
    int n = l * 64 + i;
    const float* pp = part + (size_t)n * 512 + tid;
    cv[i] = pp[0] + pp[524288] + pp[2 * 524288] + pp[3 * 524288] + bdg[n];
  }
  const float* w1 = W1 + l * 6 * 64;
  float h[6];
  #pragma unroll
  for (int hh = 0; hh < 6; ++hh) {
    float s = b1[l * 6 + hh];
    #pragma unroll
    for (int i = 0; i < 64; ++i) s = fmaf(cv[i], w1[hh * 64 + i], s);
    h[hh] = s;
  }
  bn512(h, wv, lane, r1, r2);
  float c[6];
  #pragma unroll
  for (int k = 0; k < 6; ++k) {
    float s = bc[l * 6 + k];
    #pragma unroll
    for (int hh = 0; hh < 6; ++hh) s = fmaf(h[hh], Wc[l * 36 + k * 6 + hh], s);
    c[k] = s;
  }
  bn512(c, wv, lane, r1, r2);
  float* o = outp + (((size_t)(l >> 2) * 512 + tid) * 24 + (l & 3) * 6);
  #pragma unroll
  for (int k = 0; k < 6; ++k) o[k] = c[k];
}

// ---------------- K4: mid term --------------------------------------------
__global__ __launch_bounds__(512) void k_mid(const float* __restrict__ gin,
                                             const float* __restrict__ W1,
                                             const float* __restrict__ b1,
                                             const float* __restrict__ Wc,
                                             const float* __restrict__ bc,
                                             float* __restrict__ outp) {
  const int l = blockIdx.x, tid = threadIdx.x;
  const int wv = tid >> 6, lane = tid & 63;
  __shared__ float r1[8][6], r2[8][6];
  const float* ci = gin + ((size_t)l * 512 + tid) * 24;
  float cv[24];
  #pragma unroll
  for (int q = 0; q < 6; ++q) *(float4*)&cv[q * 4] = ((const float4*)ci)[q];
  const float* w1 = W1 + l * 6 * 24;
  float h[6];
  #pragma unroll
  for (int hh = 0; hh < 6; ++hh) {
    float s = b1[l * 6 + hh];
    #pragma unroll
    for (int i = 0; i < 24; ++i) s = fmaf(cv[i], w1[hh * 24 + i], s);
    h[hh] = s;
  }
  bn512(h, wv, lane, r1, r2);
  float c[6];
  #pragma unroll
  for (int k = 0; k < 6; ++k) {
    float s = bc[l * 6 + k];
    #pragma unroll
    for (int hh = 0; hh < 6; ++hh) s = fmaf(h[hh], Wc[l * 36 + k * 6 + hh], s);
    c[k] = s;
  }
  bn512(c, wv, lane, r1, r2);
  float* o = outp + ((size_t)tid * 24 + l * 6);
  #pragma unroll
  for (int k = 0; k < 6; ++k) o[k] = c[k];
}

// ---------------- K5: root term -------------------------------------------
__global__ __launch_bounds__(512) void k_root(const float* __restrict__ rootin,
                                              const float* __restrict__ Wr1,
                                              const float* __restrict__ br1,
                                              const float* __restrict__ Wrc,
                                              const float* __restrict__ brc,
                                              const float* __restrict__ Wrd,
                                              const float* __restrict__ brd,
                                              float* __restrict__ r2d) {
  const int tid = threadIdx.x;
  const int wv = tid >> 6, lane = tid & 63;
  __shared__ float r1[8][6], r2[8][6];
  const float* ci = rootin + (size_t)tid * 24;
  float cv[24];
  #pragma unroll
  for (int q = 0; q < 6; ++q) *(float4*)&cv[q * 4] = ((const float4*)ci)[q];
  float h[6];
  #pragma unroll
  for (int hh = 0; hh < 6; ++hh) {
    float s = br1[hh];
    #pragma unroll
    for (int i = 0; i < 24; ++i) s = fmaf(cv[i], Wr1[hh * 24 + i], s);
    h[hh] = s;
  }
  bn512(h, wv, lane, r1, r2);
  float c[6];
  #pragma unroll
  for (int k = 0; k < 6; ++k) {
    float s = brc[k];
    #pragma unroll
    for (int hh = 0; hh < 6; ++hh) s = fmaf(h[hh], Wrc[k * 6 + hh], s);
    c[k] = s;
  }
  bn512(c, wv, lane, r1, r2);
  float mv = (c[0] + c[1] + c[2] + c[3] + c[4] + c[5]) * (1.0f / 6.0f);
  __shared__ float shm[512];
  shm[tid] = mv;
  __syncthreads();
  __shared__ float st[96];
  if (tid < 96) {
    int b = tid / 6, hh = tid % 6;
    float s = brd[hh];
    #pragma unroll
    for (int e = 0; e < 32; ++e) s = fmaf(shm[b * 32 + e], Wrd[hh * 32 + e], s);
    st[tid] = tanhf(s);
  }
  __syncthreads();
  if (tid < 6) {
    float S = 0.f, Q = 0.f;
    for (int b = 0; b < 16; ++b) { float v = st[b * 6 + tid]; S += v; Q += v * v; }
    float m = S * (1.0f / 16.0f), va = Q * (1.0f / 16.0f) - m * m;
    float iv = rsqrtf(va + EPSf);
    for (int b = 0; b < 16; ++b) r2d[b * 6 + tid] = (st[b * 6 + tid] - m) * iv;
  }
}

// ---------------- K6: drug layer 1 — block per column, wave per batch -----
__global__ __launch_bounds__(1024) void k_drug1(const float* __restrict__ x,
                                                const float* __restrict__ Wd1,
                                                const float* __restrict__ bd1,
                                                float* __restrict__ d1) {
  const int c = blockIdx.x;        // 0..99
  const int tid = threadIdx.x;
  const int b = tid >> 6, lane = tid & 63;
  const float* xb = x + (size_t)b * XS + Gg;
  const float* w = Wd1 + (size_t)c * 2048;
  float s = 0.f;
  #pragma unroll
  for (int q = 0; q < 8; ++q) {
    int k = q * 256 + lane * 4;
    float4 xv = *(const float4*)(xb + k);
    float4 wv = *(const float4*)(w + k);
    s = fmaf(xv.x, wv.x, s);
    s = fmaf(xv.y, wv.y, s);
    s = fmaf(xv.z, wv.z, s);
    s = fmaf(xv.w, wv.w, s);
  }
  s = wred(s);
  __shared__ float y[16];
  if (lane == 0) y[b] = tanhf(s + bd1[c]);
  __syncthreads();
  if (tid < 16) {
    float S = 0.f, Q = 0.f;
    #pragma unroll
    for (int bb = 0; bb < 16; ++bb) { float v = y[bb]; S += v; Q += v * v; }
    float m = S * (1.0f / 16.0f), va = Q * (1.0f / 16.0f) - m * m;
    d1[tid * 100 + c] = (y[tid] - m) * rsqrtf(va + EPSf);
  }
}

// ---------------- K7: drug layers 2-3 + final head -------------------------
__global__ __launch_bounds__(512) void k_final(const float* __restrict__ d1,
                                               const float* __restrict__ r2d,
                                               const float* __restrict__ Wd2,
                                               const float* __restrict__ bd2,
                                               const float* __restrict__ Wd3,
                                               const float* __restrict__ bd3,
                                               const float* __restrict__ Wf,
                                               const float* __restrict__ bf,
                                               const float* __restrict__ Wfa,
                                               const float* __restrict__ bfa,
                                               const float* __restrict__ Wfo,
                                               const float* __restrict__ bfo,
                                               float* __restrict__ out) {
  const int tid = threadIdx.x;
  __shared__ float s2[800], mu2[50], iv2[50];
  for (int u = tid; u < 800; u += 512) {
    int b = u / 50, c = u % 50;
    float s = bd2[c];
    for (int k = 0; k < 100; ++k) s = fmaf(d1[b * 100 + k], Wd2[c * 100 + k], s);
    s2[u] = tanhf(s);
  }
  __syncthreads();
  if (tid < 50) {
    float S = 0.f, Q = 0.f;
    #pragma unroll
    for (int b = 0; b < 16; ++b) { float v = s2[b * 50 + tid]; S += v; Q += v * v; }
    float m = S * (1.0f / 16.0f), va = Q * (1.0f / 16.0f) - m * m;
    mu2[tid] = m; iv2[tid] = rsqrtf(va + EPSf);
  }
  __syncthreads();
  __shared__ float s3[96], mu3[6], iv3[6];
  if (tid < 96) {
    int b = tid / 6, c = tid % 6;
    float s = bd3[c];
    for (int k = 0; k < 50; ++k)
      s = fmaf((s2[b * 50 + k] - mu2[k]) * iv2[k], Wd3[c * 50 + k], s);
    s3[tid] = tanhf(s);
  }
  __syncthreads();
  if (tid < 6) {
    float S = 0.f, Q = 0.f;
    #pragma unroll
    for (int b = 0; b < 16; ++b) { float v = s3[b * 6 + tid]; S += v; Q += v * v; }
    float m = S * (1.0f / 16.0f), va = Q * (1.0f / 16.0f) - m * m;
    mu3[tid] = m; iv3[tid] = rsqrtf(va + EPSf);
  }
  __syncthreads();
  __shared__ float sf[96], muf[6], ivf[6];
  if (tid < 96) {
    int b = tid / 6, c = tid % 6;
    float s = bf[c];
    #pragma unroll
    for (int q = 0; q < 6; ++q) s = fmaf(r2d[b * 6 + q], Wf[c * 12 + q], s);
    #pragma unroll
    for (int q = 0; q < 6; ++q)
      s = fmaf((s3[b * 6 + q] - mu3[q]) * iv3[q], Wf[c * 12 + 6 + q], s);
    sf[tid] = tanhf(s);
  }
  __syncthreads();
  if (tid < 6) {
    float S = 0.f, Q = 0.f;
    #pragma unroll
    for (int b = 0; b < 16; ++b) { float v = sf[b * 6 + tid]; S += v; Q += v * v; }
    float m = S * (1.0f / 16.0f), va = Q * (1.0f / 16.0f) - m * m;
    muf[tid] = m; ivf[tid] = rsqrtf(va + EPSf);
  }
  __syncthreads();
  if (tid < 16) {
    float s = bfa[0];
    #pragma unroll
    for (int q = 0; q < 6; ++q)
      s = fmaf((sf[tid * 6 + q] - muf[q]) * ivf[q], Wfa[q], s);
    float a = tanhf(s);
    out[tid] = a * Wfo[0] + bfo[0];
  }
}

extern "C" void kernel_launch(void* const* d_in, const int* in_sizes, int n_in,
                              void* d_out, int out_size, void* d_ws, size_t ws_size,
                              hipStream_t stream) {
  const float* x     = (const float*)d_in[0];
  const int*   table = (const int*)d_in[1];
  const float* Wrbf  = (const float*)d_in[2];
  const float* brbf  = (const float*)d_in[3];
  const float* emb   = (const float*)d_in[4];
  const float* Wdg   = (const float*)d_in[5];
  const float* bdg   = (const float*)d_in[6];
  const float* Wl1   = (const float*)d_in[7];
  const float* bl1   = (const float*)d_in[8];
  const float* Wlc   = (const float*)d_in[9];
  const float* blc   = (const float*)d_in[10];
  const float* Wm1   = (const float*)d_in[13];
  const float* bm1   = (const float*)d_in[14];
  const float* Wmc   = (const float*)d_in[15];
  const float* bmc   = (const float*)d_in[16];
  const float* Wr1   = (const float*)d_in[19];
  const float* br1   = (const float*)d_in[20];
  const float* Wrc   = (const float*)d_in[21];
  const float* brc   = (const float*)d_in[22];
  const float* Wrd   = (const float*)d_in[23];
  const float* brd   = (const float*)d_in[24];
  const float* Wd1   = (const float*)d_in[25];
  const float* bd1   = (const float*)d_in[26];
  const float* Wd2   = (const float*)d_in[27];
  const float* bd2   = (const float*)d_in[28];
  const float* Wd3   = (const float*)d_in[29];
  const float* bd3   = (const float*)d_in[30];
  const float* Wf    = (const float*)d_in[31];
  const float* bf    = (const float*)d_in[32];
  const float* Wfa   = (const float*)d_in[33];
  const float* bfa   = (const float*)d_in[34];
  const float* Wfo   = (const float*)d_in[35];
  const float* bfo   = (const float*)d_in[36];
  float* out = (float*)d_out;

  u32* Rhi = (u32*)d_ws;                   // 32768
  u32* Rlo = Rhi + 32768;                  // 32768
  u32* Dhi = Rlo + 32768;                  // 1048576
  u32* Dlo = Dhi + 1048576;                // 1048576
  u32* Ahi = Dlo + 1048576;                // 524288
  u32* Alo = Ahi + 524288;                 // 524288
  float* partB = (float*)(Alo + 524288);   // 4 * 524288
  float* midin = partB + 4 * 524288;       // 49152
  float* rootin= midin + 49152;            // 12288
  float* r2d   = rootin + 12288;           // 96
  float* d1    = r2d + 96;                 // 1600

  hipLaunchKernelGGL(k_split, dim3(1056),   dim3(256),  0, stream, Wrbf, Wdg, Rhi, Rlo, Dhi, Dlo);
  hipLaunchKernelGGL(k_rbf,   dim3(16, 16), dim3(512),  0, stream, x, Rhi, Rlo, table, emb, brbf, Ahi, Alo);
  hipLaunchKernelGGL(k_mm,    dim3(256),    dim3(256),  0, stream, Ahi, Alo, Dhi, Dlo, partB);
  hipLaunchKernelGGL(k_leaf,  dim3(16),     dim3(512),  0, stream, partB, bdg, Wl1, bl1, Wlc, blc, midin);
  hipLaunchKernelGGL(k_mid,   dim3(4),      dim3(512),  0, stream, midin, Wm1, bm1, Wmc, bmc, rootin);
  hipLaunchKernelGGL(k_root,  dim3(1),      dim3(512),  0, stream, rootin, Wr1, br1, Wrc, brc, Wrd, brd, r2d);
  hipLaunchKernelGGL(k_drug1, dim3(100),    dim3(1024), 0, stream, x, Wd1, bd1, d1);
  hipLaunchKernelGGL(k_final, dim3(1),      dim3(512),  0, stream, d1, r2d, Wd2, bd2, Wd3, bd3,
                     Wf, bf, Wfa, bfa, Wfo, bfo, out);
}